// Round 15
// baseline (63.691 us; speedup 1.0000x reference)
//
#include <hip/hip_runtime.h>

// B=2, H=16, S=2048, D=64, fp32 in/out, causal (mask input ignored; computed analytically).
#define S_LEN 2048
#define DHEAD 64
#define KVTILE 64
#define TBUF  16384    // one tile buf: K 8192B + Vt 8192B (128B rows, 16B-slot XOR swizzle)
#define VOFF  8192
#define PSTRIDE 32768  // parity stride = 2 buffers (double-buffered)
#define OPART 8704     // combine (overlays dead K/V bufs): per-qg O-partial stride
#define LSOFF 34816    // combine: lsum region

// d_ws: O-partials 256 split q-tiles x 2 chunks x 8192 f32 = 16777216 B
//       l-partials at +16777216: 256 x 2 x 128 f32 = 262144 B
#define WS_LBASE 16777216
#define WS_NEED  17039360ull

typedef float          f32x4  __attribute__((ext_vector_type(4)));
typedef float          f32x16 __attribute__((ext_vector_type(16)));
typedef unsigned int   u32x2  __attribute__((ext_vector_type(2)));
typedef unsigned int   u32x4  __attribute__((ext_vector_type(4)));
typedef __bf16         bf16x8 __attribute__((ext_vector_type(8)));

__device__ __forceinline__ unsigned int pack_bf16(float lo, float hi) {
  return __builtin_amdgcn_perm(__builtin_bit_cast(unsigned int, hi),
                               __builtin_bit_cast(unsigned int, lo),
                               0x07060302u);
}

// r13 lesson: NO per-block device-scope fences/atomics (L2 writeback storms on
// non-coherent XCD L2s, 5x). Cross-block combine goes through a SECOND KERNEL:
// the kernel boundary is one amortized flush.
// MODE 0: r12 whole-tile mapping (512 blocks) — ws-less fallback.
// MODE 1: 768 blocks, descending-ss dispatch: q-tiles qt2>=8 split into two
//         kv-chunks of (qt2+1) tiles; qt2<=7 whole. Split blocks write (O,l)
//         partials to ws; combine_kernel finishes them.
template <int MODE>
__global__ __launch_bounds__(512, 2)
void attn_fwd_kernel(const float* __restrict__ qg_, const float* __restrict__ kg,
                     const float* __restrict__ vg, float* __restrict__ og,
                     float* __restrict__ wsO, float* __restrict__ wsL)
{
  __shared__ __align__(16) unsigned char smem[65536];

  const int tid  = threadIdx.x;
  const int lane = tid & 63;
  const int l31  = lane & 31;    // q (QK/PV out col), kv-row (K frag), d-row (V frag)
  const int hi   = lane >> 5;    // k-half selector of 32x32x16 fragments
  const int wid  = tid >> 6;     // 0..7
  const int qg   = wid & 3;      // q-group (32 rows each)
  const int par  = wid >> 2;     // kv-tile parity this wave computes

  const int bid = blockIdx.x;
  int qt2, bh, t0, t1, half = 0, qi = 0;
  bool split = false;
  if (MODE) {
    // group g = bid>>5, descending super-step count (LPT backfill order).
    static const signed char qt2_tab[24]  = {15,15,14,14, 7,13,13,12,12, 6,
                                             11,11,10,10, 5, 9, 9, 8, 8, 4,
                                              3, 2, 1, 0};
    static const signed char half_tab[24] = { 0, 1, 0, 1,-1, 0, 1, 0, 1,-1,
                                              0, 1, 0, 1,-1, 0, 1, 0, 1,-1,
                                             -1,-1,-1,-1};
    const int g = bid >> 5;
    bh  = bid & 31;              // head: bid&31 -> 4 heads/XCD (L2-resident K/V)
    qt2 = qt2_tab[g];
    const int h = half_tab[g];
    if (h < 0) { t0 = 0; t1 = 2 * qt2 + 2; }
    else {
      split = true; half = h;
      const int C = qt2 + 1;     // kv-tiles per chunk
      t0 = h * C;  t1 = t0 + C;
      qi = (qt2 - 8) * 32 + bh;
    }
  } else {
    bh = bid & 31;
    const int r = bid >> 5;
    qt2 = (r < 8) ? r : 23 - r;
    t0 = 0;  t1 = 2 * qt2 + 2;
  }
  const int nss = (t1 - t0 + 1) >> 1;    // super-steps (2 tiles each)

  const int q0w = qt2 * 128 + qg * 32;   // this wave's 32 q-rows
  const int tb  = 2 * qt2 + (qg >> 1);   // wave's diagonal (causal-bound) tile, global

  const float* qp = qg_ + (size_t)bh * S_LEN * DHEAD;
  const float* kp = kg  + (size_t)bh * S_LEN * DHEAD;
  const float* vp = vg  + (size_t)bh * S_LEN * DHEAD;
  float*       op = og  + (size_t)bh * S_LEN * DHEAD;

  // staging: threads [0,256) stage even-slot tiles, [256,512) odd-slot tiles
  const int sh   = tid >> 8;
  const int stid = tid & 255;
  const int krow = stid >> 2;                       // K: row, 16 f32 at kd0
  const int kc2  = stid & 3;
  const int kd0  = kc2 * 16;
  const int va   = ((stid >> 6) << 2) | (stid & 3); // V: 4x4 block col (kv/4)
  const int vm   = (stid >> 2) & 15;                // V: 4x4 block row (d/4)

  f32x4 kxr[4];   // K prefetch (held across compute)
  f32x4 vxr[4];   // V prefetch (issued between halves)

  auto load_k = [&](int kv0) {
    #pragma unroll
    for (int i = 0; i < 4; ++i)
      kxr[i] = *reinterpret_cast<const f32x4*>(
          kp + (size_t)(kv0 + krow) * DHEAD + kd0 + 4 * i);
  };
  auto load_v = [&](int kv0) {
    #pragma unroll
    for (int j = 0; j < 4; ++j)
      vxr[j] = *reinterpret_cast<const f32x4*>(
          vp + (size_t)(kv0 + 4 * va + j) * DHEAD + 4 * vm);
  };

  auto stage_kv = [&](int buf) {
    unsigned char* kb = smem + sh * PSTRIDE + buf * TBUF;
    const int k7 = krow & 7;
    u32x4 w0, w1;   // K row-major: 16 f32 -> 2 swizzled b128 writes
    w0[0] = pack_bf16(kxr[0][0], kxr[0][1]); w0[1] = pack_bf16(kxr[0][2], kxr[0][3]);
    w0[2] = pack_bf16(kxr[1][0], kxr[1][1]); w0[3] = pack_bf16(kxr[1][2], kxr[1][3]);
    w1[0] = pack_bf16(kxr[2][0], kxr[2][1]); w1[1] = pack_bf16(kxr[2][2], kxr[2][3]);
    w1[2] = pack_bf16(kxr[3][0], kxr[3][1]); w1[3] = pack_bf16(kxr[3][2], kxr[3][3]);
    *reinterpret_cast<u32x4*>(kb + krow * 128 + (((kc2 << 1)    ) ^ k7) * 16) = w0;
    *reinterpret_cast<u32x4*>(kb + krow * 128 + (((kc2 << 1) + 1) ^ k7) * 16) = w1;
    unsigned char* vb = kb + VOFF;   // V^T, thread-local 4x4 transpose, swizzled 8B writes
    #pragma unroll
    for (int c = 0; c < 4; ++c) {
      const int d = 4 * vm + c;
      u32x2 w;
      w[0] = pack_bf16(vxr[0][c], vxr[1][c]);
      w[1] = pack_bf16(vxr[2][c], vxr[3][c]);
      *reinterpret_cast<u32x2*>(
          vb + d * 128 + (((va >> 1) ^ (d & 7)) * 16) + (va & 1) * 8) = w;
    }
  };

  // ---- Q fragments (B-operand of swapped QK): Q[q0w+l31][dstep*16+hi*8+j] * qscale ----
  const float qscale = 0.125f * 1.44269504f;   // 1/sqrt(64) * log2(e): p = exp2(s)
  bf16x8 qf[4];
  #pragma unroll
  for (int dstep = 0; dstep < 4; ++dstep) {
    const f32x4* src = reinterpret_cast<const f32x4*>(
        qp + (size_t)(q0w + l31) * DHEAD + dstep * 16 + hi * 8);
    f32x4 x0 = src[0];
    f32x4 x1 = src[1];
    u32x4 qw;
    qw[0] = pack_bf16(x0[0] * qscale, x0[1] * qscale);
    qw[1] = pack_bf16(x0[2] * qscale, x0[3] * qscale);
    qw[2] = pack_bf16(x1[0] * qscale, x1[1] * qscale);
    qw[3] = pack_bf16(x1[2] * qscale, x1[3] * qscale);
    qf[dstep] = __builtin_bit_cast(bf16x8, qw);
  }

  f32x16 oacc[2] = {};   // O^T partial: oacc[dh] reg r -> O[q0w+l31][dh*32+(r&3)+8*(r>>2)+4*hi]
  float lsum = 0.f;

  load_k((t0 + sh) * KVTILE);    // prologue: stage chunk tiles t0, t0+1
  load_v((t0 + sh) * KVTILE);
  stage_kv(0);
  __syncthreads();

  // One 32-kv half: QK(4 MFMA) -> softmax -> 2 pfrags -> PV(4 MFMA). (r12 body)
  auto process_half = [&](int a, int limit, bool diag,
                          unsigned char* kbase, unsigned char* vbase) {
    f32x16 sacc = {};
    __builtin_amdgcn_s_setprio(1);
    #pragma unroll
    for (int dstep = 0; dstep < 4; ++dstep) {
      bf16x8 kf = *reinterpret_cast<const bf16x8*>(
          kbase + (a * 32 + l31) * 128 + (((dstep << 1) + hi) ^ (l31 & 7)) * 16);
      sacc = __builtin_amdgcn_mfma_f32_32x32x16_bf16(kf, qf[dstep], sacc, 0, 0, 0);
    }
    __builtin_amdgcn_s_setprio(0);

    unsigned int w0[4], w1[4];   // softmax: p = exp2(s); mask ONLY on the diag tile
    #pragma unroll
    for (int g = 0; g < 4; ++g) {
      float p[4];
      #pragma unroll
      for (int i = 0; i < 4; ++i)
        p[i] = __builtin_amdgcn_exp2f(sacc[4 * g + i]);
      if (diag) {        // wave-uniform branch: 90% of tiles skip the 32 cndmasks
        #pragma unroll
        for (int i = 0; i < 4; ++i)
          if (a * 32 + 8 * g + 4 * hi + i > limit) p[i] = 0.f;
      }
      lsum += (p[0] + p[1]) + (p[2] + p[3]);
      w0[g] = pack_bf16(p[0], p[1]);
      w1[g] = pack_bf16(p[2], p[3]);
    }

    // In-register P-fragment assembly via shfl_xor(32) half-exchange (r9-verified):
    // consumer (l31,hi), ks=2a+b needs elem j = P[q][32a+16b+8hi+j].
    bf16x8 pfrag[2];
    #pragma unroll
    for (int b = 0; b < 2; ++b) {
      const unsigned int x0 = w0[2 * b], y0 = w0[2 * b + 1];
      const unsigned int x1 = w1[2 * b], y1 = w1[2 * b + 1];
      const unsigned int sx0 = (unsigned int)__shfl_xor((int)x0, 32, 64);
      const unsigned int sy0 = (unsigned int)__shfl_xor((int)y0, 32, 64);
      const unsigned int sx1 = (unsigned int)__shfl_xor((int)x1, 32, 64);
      const unsigned int sy1 = (unsigned int)__shfl_xor((int)y1, 32, 64);
      u32x4 f;
      f[0] = hi ? sy0 : x0;
      f[1] = hi ? sy1 : x1;
      f[2] = hi ? y0 : sx0;
      f[3] = hi ? y1 : sx1;
      pfrag[b] = __builtin_bit_cast(bf16x8, f);
    }

    __builtin_amdgcn_s_setprio(1);
    #pragma unroll
    for (int dh = 0; dh < 2; ++dh) {
      const int d = dh * 32 + l31;
      #pragma unroll
      for (int b = 0; b < 2; ++b) {
        bf16x8 vf = *reinterpret_cast<const bf16x8*>(
            vbase + d * 128 + ((((2 * a + b) << 1) + hi) ^ (l31 & 7)) * 16);
        oacc[dh] = __builtin_amdgcn_mfma_f32_32x32x16_bf16(vf, pfrag[b], oacc[dh], 0, 0, 0);
      }
    }
    __builtin_amdgcn_s_setprio(0);
  };

  for (int s = 0; s < nss; ++s) {
    const int cur = s & 1;
    const bool more = (s + 1 < nss);
    unsigned char* kbase = smem + par * PSTRIDE + cur * TBUF;
    unsigned char* vbase = kbase + VOFF;

    if (more) {   // next-pair prefetch; clamp keeps odd-length chunk tails in range
      const int pk = t0 + 2 * s + 2 + sh;
      load_k(((pk < t1) ? pk : (t1 - 1)) * KVTILE);
    }

    const int t_w = t0 + 2 * s + par;
    const bool act = (t_w < t1) && (t_w <= tb);
    const int limit = q0w + l31 - t_w * KVTILE;
    const bool diag = (t_w == tb);

    if (act) process_half(0, limit, diag, kbase, vbase);
    if (more) {
      const int pv = t0 + 2 * s + 2 + sh;
      load_v(((pv < t1) ? pv : (t1 - 1)) * KVTILE);
    }
    if (act) process_half(1, limit, diag, kbase, vbase);

    if (more) stage_kv(cur ^ 1);   // overlaps other waves' compute

    __syncthreads();               // single barrier per super-step
  }

  // ---- intra-block parity combine (linear) + store (direct or ws-partials) ----
  float ls2 = lsum + __shfl_xor(lsum, 32, 64);
  if (par == 0) {
    unsigned char* ob = smem + qg * OPART + l31 * 272;
    #pragma unroll
    for (int dh = 0; dh < 2; ++dh)
      #pragma unroll
      for (int m = 0; m < 4; ++m) {
        f32x4 o;
        #pragma unroll
        for (int i = 0; i < 4; ++i) o[i] = oacc[dh][4 * m + i];
        *reinterpret_cast<f32x4*>(ob + (dh * 32 + 8 * m + 4 * hi) * 4) = o;
      }
    if (hi == 0)
      *reinterpret_cast<float*>(smem + LSOFF + qg * 128 + l31 * 4) = ls2;
  }
  __syncthreads();
  if (par == 1) {
    const float ltot = ls2 +
        *reinterpret_cast<const float*>(smem + LSOFF + qg * 128 + l31 * 4);
    unsigned char* ob = smem + qg * OPART + l31 * 272;
    #pragma unroll
    for (int dh = 0; dh < 2; ++dh)
      #pragma unroll
      for (int m = 0; m < 4; ++m) {
        const f32x4 part = *reinterpret_cast<const f32x4*>(
            ob + (dh * 32 + 8 * m + 4 * hi) * 4);
        #pragma unroll
        for (int i = 0; i < 4; ++i) oacc[dh][4 * m + i] += part[i];
      }
    if (MODE && split) {
      float* po = wsO + (size_t)(qi * 2 + half) * 8192 + (qg * 32 + l31) * 64;
      #pragma unroll
      for (int dh = 0; dh < 2; ++dh)
        #pragma unroll
        for (int m = 0; m < 4; ++m) {
          f32x4 o;
          #pragma unroll
          for (int i = 0; i < 4; ++i) o[i] = oacc[dh][4 * m + i];
          *reinterpret_cast<f32x4*>(po + dh * 32 + 8 * m + 4 * hi) = o;
        }
      if (hi == 0) wsL[(qi * 2 + half) * 128 + qg * 32 + l31] = ltot;
    } else {
      const float rl = 1.0f / ltot;
      #pragma unroll
      for (int dh = 0; dh < 2; ++dh)
        #pragma unroll
        for (int m = 0; m < 4; ++m) {
          f32x4 o;
          #pragma unroll
          for (int i = 0; i < 4; ++i) o[i] = oacc[dh][4 * m + i] * rl;
          *reinterpret_cast<f32x4*>(
              op + (size_t)(q0w + l31) * DHEAD + dh * 32 + 8 * m + 4 * hi) = o;
        }
    }
  }
}

// Finishes the 256 split q-tiles: out = (O0 + O1) / (l0 + l1). Deterministic
// 2-addend sum; stream ordering (kernel boundary) provides coherence — no
// fences, no atomics.
__global__ __launch_bounds__(256, 8)
void combine_kernel(const float* __restrict__ wsO, const float* __restrict__ wsL,
                    float* __restrict__ og)
{
  const int qi  = blockIdx.x;          // 0..255
  const int qt2 = 8 + (qi >> 5);
  const int bh  = qi & 31;
  const int tid = threadIdx.x;
  const int row = tid >> 1;            // 0..127
  const int cb  = (tid & 1) * 32;

  const float l0 = wsL[(qi * 2    ) * 128 + row];
  const float l1 = wsL[(qi * 2 + 1) * 128 + row];
  const float rl = 1.0f / (l0 + l1);

  const float* p0 = wsO + (size_t)(qi * 2) * 8192 + row * 64 + cb;
  const float* p1 = p0 + 8192;
  float* o = og + ((size_t)bh * S_LEN + qt2 * 128 + row) * DHEAD + cb;

  #pragma unroll
  for (int c = 0; c < 8; ++c) {
    const f32x4 a = *reinterpret_cast<const f32x4*>(p0 + 4 * c);
    const f32x4 b = *reinterpret_cast<const f32x4*>(p1 + 4 * c);
    f32x4 r;
    #pragma unroll
    for (int i = 0; i < 4; ++i) r[i] = (a[i] + b[i]) * rl;
    *reinterpret_cast<f32x4*>(o + 4 * c) = r;
  }
}

extern "C" void kernel_launch(void* const* d_in, const int* in_sizes, int n_in,
                              void* d_out, int out_size, void* d_ws, size_t ws_size,
                              hipStream_t stream) {
  const float* q = (const float*)d_in[0];
  const float* k = (const float*)d_in[1];
  const float* v = (const float*)d_in[2];
  // d_in[3]: causal mask — always tril, computed analytically in-kernel.
  float* out = (float*)d_out;

  float* wsO = (float*)d_ws;
  float* wsL = (float*)((char*)d_ws + WS_LBASE);

  if (ws_size >= WS_NEED) {
    attn_fwd_kernel<1><<<dim3(768), dim3(512), 0, stream>>>(q, k, v, out, wsO, wsL);
    combine_kernel<<<dim3(256), dim3(256), 0, stream>>>(wsO, wsL, out);
  } else {
    attn_fwd_kernel<0><<<dim3(512), dim3(512), 0, stream>>>(q, k, v, out, wsO, wsL);
  }
}

// Round 16
// 63.635 us; speedup vs baseline: 1.0009x; 1.0009x over previous
//
#include <hip/hip_runtime.h>

// B=2, H=16, S=2048, D=64, fp32 in/out, causal (mask input ignored; computed analytically).
#define S_LEN 2048
#define DHEAD 64
#define KVTILE 64
#define TBUF  16384    // one tile buf: K 8192B + Vt 8192B (128B rows, 16B-slot XOR swizzle)
#define VOFF  8192
#define PSTRIDE 32768  // parity stride = 2 buffers (double-buffered)

typedef float          f32x4  __attribute__((ext_vector_type(4)));
typedef float          f32x16 __attribute__((ext_vector_type(16)));
typedef unsigned int   u32x2  __attribute__((ext_vector_type(2)));
typedef unsigned int   u32x4  __attribute__((ext_vector_type(4)));
typedef __bf16         bf16x8 __attribute__((ext_vector_type(8)));

// Pack two fp32 into (bf16(hi)<<16)|bf16(lo) by byte-perm truncation: 1 VALU op / 2 values.
__device__ __forceinline__ unsigned int pack_bf16(float lo, float hi) {
  return __builtin_amdgcn_perm(__builtin_bit_cast(unsigned int, hi),
                               __builtin_bit_cast(unsigned int, lo),
                               0x07060302u);
}

// r16: 1024-thread blocks on 256-row q-tiles. History: critical blocks ran at
// 1 block/CU = 2 waves/SIMD (r6's balanced 23.7% occupancy ≈ exactly 25%);
// kv-splitting failed twice (r13 fences 5x, r15 partials polluted L2). This
// doubles waves/SIMD on the critical path instead: 16 waves/block, 4/SIMD,
// launch_bounds(1024,1) -> 128-reg cap (arg2 = blocks/CU, r8-r11 evidence).
__global__ __launch_bounds__(1024, 1)
void attn_fwd_kernel(const float* __restrict__ qg_, const float* __restrict__ kg,
                     const float* __restrict__ vg, float* __restrict__ og)
{
  __shared__ __align__(16) unsigned char smem[65536];

  const int tid  = threadIdx.x;
  const int lane = tid & 63;
  const int l31  = lane & 31;    // q (QK/PV out col), kv-row (K frag), d-row (V frag)
  const int hi   = lane >> 5;    // k-half selector of 32x32x16 fragments
  const int wid  = tid >> 6;     // 0..15
  const int qg   = wid & 7;      // q-group (32 rows each, 8 groups = 256 rows)
  const int par  = wid >> 3;     // kv-tile parity this wave computes

  // 256 blocks = 8 q-tiles x 32 heads, one per CU. bh=bid&31 -> 4 heads/XCD
  // (L2-resident K/V, r6-verified).
  const int bid = blockIdx.x;
  const int bh  = bid & 31;
  const int qtp = bid >> 5;              // 256-row q-tile index 0..7

  const int q0w = qtp * 256 + qg * 32;   // this wave's 32 q-rows
  const int tb  = 4 * qtp + (qg >> 1);   // wave's diagonal (causal-bound) tile
  const int nss = 2 * qtp + 2;           // super-steps (2 tiles each); t1 = 4qtp+4

  const float* qp = qg_ + (size_t)bh * S_LEN * DHEAD;
  const float* kp = kg  + (size_t)bh * S_LEN * DHEAD;
  const float* vp = vg  + (size_t)bh * S_LEN * DHEAD;
  float*       op = og  + (size_t)bh * S_LEN * DHEAD;

  // staging: 512 threads per parity tile; within, 256 stage K and 256 stage V
  // (role-split: each thread loads/packs only 16 f32 -> rx[4], saves 16 VGPR).
  const int sh    = tid >> 9;            // == par for the owning waves
  const int stid  = tid & 511;
  const bool krole = (stid < 256);
  const int s8    = stid & 255;
  const int krow  = s8 >> 2;                      // K: row, 16 f32 at kd0
  const int kc2   = s8 & 3;
  const int kd0   = kc2 * 16;
  const int va    = ((s8 >> 6) << 2) | (s8 & 3);  // V: 4x4 block col (kv/4)
  const int vm    = (s8 >> 2) & 15;               // V: 4x4 block row (d/4)

  f32x4 rx[4];   // staging prefetch (K row chunk OR V 4x4 block, per role)

  auto load_tile = [&](int kv0) {
    if (krole) {
      #pragma unroll
      for (int i = 0; i < 4; ++i)
        rx[i] = *reinterpret_cast<const f32x4*>(
            kp + (size_t)(kv0 + krow) * DHEAD + kd0 + 4 * i);
    } else {
      #pragma unroll
      for (int j = 0; j < 4; ++j)
        rx[j] = *reinterpret_cast<const f32x4*>(
            vp + (size_t)(kv0 + 4 * va + j) * DHEAD + 4 * vm);
    }
  };

  auto stage_kv = [&](int buf) {
    unsigned char* kb = smem + sh * PSTRIDE + buf * TBUF;
    if (krole) {
      const int k7 = krow & 7;
      u32x4 w0, w1;   // K row-major: 16 f32 -> 2 swizzled b128 writes
      w0[0] = pack_bf16(rx[0][0], rx[0][1]); w0[1] = pack_bf16(rx[0][2], rx[0][3]);
      w0[2] = pack_bf16(rx[1][0], rx[1][1]); w0[3] = pack_bf16(rx[1][2], rx[1][3]);
      w1[0] = pack_bf16(rx[2][0], rx[2][1]); w1[1] = pack_bf16(rx[2][2], rx[2][3]);
      w1[2] = pack_bf16(rx[3][0], rx[3][1]); w1[3] = pack_bf16(rx[3][2], rx[3][3]);
      *reinterpret_cast<u32x4*>(kb + krow * 128 + (((kc2 << 1)    ) ^ k7) * 16) = w0;
      *reinterpret_cast<u32x4*>(kb + krow * 128 + (((kc2 << 1) + 1) ^ k7) * 16) = w1;
    } else {
      unsigned char* vb = kb + VOFF;   // V^T via thread-local 4x4 transpose
      #pragma unroll
      for (int c = 0; c < 4; ++c) {
        const int d = 4 * vm + c;
        u32x2 w;
        w[0] = pack_bf16(rx[0][c], rx[1][c]);
        w[1] = pack_bf16(rx[2][c], rx[3][c]);
        *reinterpret_cast<u32x2*>(
            vb + d * 128 + (((va >> 1) ^ (d & 7)) * 16) + (va & 1) * 8) = w;
      }
    }
  };

  // ---- Q fragments (B-operand of swapped QK): Q[q0w+l31][dstep*16+hi*8+j] * qscale ----
  const float qscale = 0.125f * 1.44269504f;   // 1/sqrt(64) * log2(e): p = exp2(s)
  bf16x8 qf[4];
  #pragma unroll
  for (int dstep = 0; dstep < 4; ++dstep) {
    const f32x4* src = reinterpret_cast<const f32x4*>(
        qp + (size_t)(q0w + l31) * DHEAD + dstep * 16 + hi * 8);
    f32x4 x0 = src[0];
    f32x4 x1 = src[1];
    u32x4 qw;
    qw[0] = pack_bf16(x0[0] * qscale, x0[1] * qscale);
    qw[1] = pack_bf16(x0[2] * qscale, x0[3] * qscale);
    qw[2] = pack_bf16(x1[0] * qscale, x1[1] * qscale);
    qw[3] = pack_bf16(x1[2] * qscale, x1[3] * qscale);
    qf[dstep] = __builtin_bit_cast(bf16x8, qw);
  }

  f32x16 oacc[2] = {};   // O^T partial: oacc[dh] reg r -> O[q0w+l31][dh*32+(r&3)+8*(r>>2)+4*hi]
  float lsum = 0.f;

  load_tile(sh * KVTILE);    // prologue: stage tiles 0 and 1 into buf 0
  stage_kv(0);
  __syncthreads();

  // One 32-kv half: QK(4 MFMA) -> softmax -> 2 pfrags -> PV(4 MFMA). (r12 body,
  // diag-gated masking from r15.)
  auto process_half = [&](int a, int limit, bool diag,
                          unsigned char* kbase, unsigned char* vbase) {
    f32x16 sacc = {};
    __builtin_amdgcn_s_setprio(1);
    #pragma unroll
    for (int dstep = 0; dstep < 4; ++dstep) {
      bf16x8 kf = *reinterpret_cast<const bf16x8*>(
          kbase + (a * 32 + l31) * 128 + (((dstep << 1) + hi) ^ (l31 & 7)) * 16);
      sacc = __builtin_amdgcn_mfma_f32_32x32x16_bf16(kf, qf[dstep], sacc, 0, 0, 0);
    }
    __builtin_amdgcn_s_setprio(0);

    unsigned int w0[4], w1[4];   // softmax: p = exp2(s); mask ONLY on the diag tile
    #pragma unroll
    for (int g = 0; g < 4; ++g) {
      float p[4];
      #pragma unroll
      for (int i = 0; i < 4; ++i)
        p[i] = __builtin_amdgcn_exp2f(sacc[4 * g + i]);
      if (diag) {        // wave-uniform: ~90% of tiles skip the 32 cndmasks
        #pragma unroll
        for (int i = 0; i < 4; ++i)
          if (a * 32 + 8 * g + 4 * hi + i > limit) p[i] = 0.f;
      }
      lsum += (p[0] + p[1]) + (p[2] + p[3]);
      w0[g] = pack_bf16(p[0], p[1]);
      w1[g] = pack_bf16(p[2], p[3]);
    }

    // In-register P-fragment assembly via shfl_xor(32) half-exchange (r9-verified):
    // consumer (l31,hi), ks=2a+b needs elem j = P[q][32a+16b+8hi+j].
    bf16x8 pfrag[2];
    #pragma unroll
    for (int b = 0; b < 2; ++b) {
      const unsigned int x0 = w0[2 * b], y0 = w0[2 * b + 1];
      const unsigned int x1 = w1[2 * b], y1 = w1[2 * b + 1];
      const unsigned int sx0 = (unsigned int)__shfl_xor((int)x0, 32, 64);
      const unsigned int sy0 = (unsigned int)__shfl_xor((int)y0, 32, 64);
      const unsigned int sx1 = (unsigned int)__shfl_xor((int)x1, 32, 64);
      const unsigned int sy1 = (unsigned int)__shfl_xor((int)y1, 32, 64);
      u32x4 f;
      f[0] = hi ? sy0 : x0;
      f[1] = hi ? sy1 : x1;
      f[2] = hi ? y0 : sx0;
      f[3] = hi ? y1 : sx1;
      pfrag[b] = __builtin_bit_cast(bf16x8, f);
    }

    __builtin_amdgcn_s_setprio(1);
    #pragma unroll
    for (int dh = 0; dh < 2; ++dh) {
      const int d = dh * 32 + l31;
      #pragma unroll
      for (int b = 0; b < 2; ++b) {
        bf16x8 vf = *reinterpret_cast<const bf16x8*>(
            vbase + d * 128 + ((((2 * a + b) << 1) + hi) ^ (l31 & 7)) * 16);
        oacc[dh] = __builtin_amdgcn_mfma_f32_32x32x16_bf16(vf, pfrag[b], oacc[dh], 0, 0, 0);
      }
    }
    __builtin_amdgcn_s_setprio(0);
  };

  for (int s = 0; s < nss; ++s) {
    const int cur = s & 1;
    const bool more = (s + 1 < nss);
    unsigned char* kbase = smem + par * PSTRIDE + cur * TBUF;
    unsigned char* vbase = kbase + VOFF;

    if (more) load_tile((2 * s + 2 + sh) * KVTILE);   // next-pair loads hide under compute

    const int t_w = 2 * s + par;
    const bool act = (t_w <= tb);
    const int limit = q0w + l31 - t_w * KVTILE;
    const bool diag = (t_w == tb);

    if (act) {
      process_half(0, limit, diag, kbase, vbase);
      process_half(1, limit, diag, kbase, vbase);
    }

    if (more) stage_kv(cur ^ 1);   // overlaps other waves' compute (other buffer)

    __syncthreads();               // single barrier per super-step
  }

  // ---- parity combine (linear), two phases (8 qg x 8.2KB > 64KB LDS).
  //      Overlays the (now dead) K/V buffers. ----
  float ls2 = lsum + __shfl_xor(lsum, 32, 64);
  const int qgl = qg & 3;
  #pragma unroll 1
  for (int phase = 0; phase < 2; ++phase) {
    if (par == 0 && (qg >> 2) == phase) {
      unsigned char* ob = smem + qgl * 8192 + l31 * 256;
      #pragma unroll
      for (int dh = 0; dh < 2; ++dh)
        #pragma unroll
        for (int m = 0; m < 4; ++m) {
          f32x4 o;
          #pragma unroll
          for (int i = 0; i < 4; ++i) o[i] = oacc[dh][4 * m + i];
          *reinterpret_cast<f32x4*>(ob + (dh * 32 + 8 * m + 4 * hi) * 4) = o;
        }
      if (hi == 0)
        *reinterpret_cast<float*>(smem + 32768 + qgl * 128 + l31 * 4) = ls2;
    }
    __syncthreads();
    if (par == 1 && (qg >> 2) == phase) {
      const float ltot = ls2 +
          *reinterpret_cast<const float*>(smem + 32768 + qgl * 128 + l31 * 4);
      const float rl = 1.0f / ltot;
      unsigned char* ob = smem + qgl * 8192 + l31 * 256;
      #pragma unroll
      for (int dh = 0; dh < 2; ++dh)
        #pragma unroll
        for (int m = 0; m < 4; ++m) {
          const f32x4 part = *reinterpret_cast<const f32x4*>(
              ob + (dh * 32 + 8 * m + 4 * hi) * 4);
          f32x4 o;
          #pragma unroll
          for (int i = 0; i < 4; ++i) o[i] = (oacc[dh][4 * m + i] + part[i]) * rl;
          *reinterpret_cast<f32x4*>(
              op + (size_t)(q0w + l31) * DHEAD + dh * 32 + 8 * m + 4 * hi) = o;
        }
    }
    __syncthreads();   // phase-1 reuses the same qgl regions
  }
}

extern "C" void kernel_launch(void* const* d_in, const int* in_sizes, int n_in,
                              void* d_out, int out_size, void* d_ws, size_t ws_size,
                              hipStream_t stream) {
  const float* q = (const float*)d_in[0];
  const float* k = (const float*)d_in[1];
  const float* v = (const float*)d_in[2];
  // d_in[3]: causal mask — always tril, computed analytically in-kernel.
  float* out = (float*)d_out;

  dim3 grid(256);    // 8 q-tiles (256 rows) x 32 heads; one 1024-thread block per CU
  dim3 block(1024);
  attn_fwd_kernel<<<grid, block, 0, stream>>>(q, k, v, out);
}